// Round 6
// baseline (861.732 us; speedup 1.0000x reference)
//
#include <hip/hip_runtime.h>
#include <math.h>

typedef unsigned short u16;
typedef __bf16 bf16x8 __attribute__((ext_vector_type(8)));
typedef float f32x4 __attribute__((ext_vector_type(4)));

#define NPACK  11264   // padded packed-pair count (88*128)
#define NVALID 10864   // 8256 + 2080 + 528
#define BASE1  8256
#define BASE2  10336

__device__ __forceinline__ u16 f2bf(float f) {
    unsigned u = __builtin_bit_cast(unsigned, f);
    u += 0x7FFFu + ((u >> 16) & 1u);
    return (u16)(u >> 16);
}
__device__ __forceinline__ float bf2f(u16 h) {
    return __builtin_bit_cast(float, ((unsigned)h) << 16);
}

#define GLOAD_LDS16(g, l)                                                     \
    __builtin_amdgcn_global_load_lds(                                         \
        (const __attribute__((address_space(1))) void*)(g),                   \
        (__attribute__((address_space(3))) void*)(l), 16, 0, 0)

// ---------------------------------------------------------------- uv table
// tab[i] = seg<<14 | u<<7 | v   for packed triangular index i (u<=v)
__global__ __launch_bounds__(256) void k_uv(int S, int lg, int base, int seg,
                                            u16* __restrict__ tab) {
    int j = blockIdx.x * 256 + threadIdx.x;
    int u = j >> lg, v = j & (S - 1);
    if (u >= S || v < u) return;
    int i = base + u * S - (u * (u - 1)) / 2 + (v - u);
    tab[i] = (u16)((seg << 14) | (u << 7) | v);
}
__global__ __launch_bounds__(256) void k_uvpad(u16* __restrict__ tab) {
    int j = blockIdx.x * 256 + threadIdx.x;
    if (NVALID + j < NPACK) tab[NVALID + j] = 0xFFFFu;
}

// ---------------------------------------------------------------- packed weights
// Wsym[i,h] = s_seg*(w[uv,h]+w[vu,h])  (diag -> 2w, features carry the 0.5)
// Wt[h,i]   = same values transposed (K-contiguous for GEMM1's B operand)
__global__ __launch_bounds__(256) void k_packw(const float* __restrict__ w0,
                                               const float* __restrict__ w1,
                                               const float* __restrict__ w2,
                                               const u16* __restrict__ tab,
                                               u16* __restrict__ Wsym,
                                               u16* __restrict__ Wt) {
    __shared__ u16 tile[32][258];
    __shared__ u16 te[32];
    int i0 = blockIdx.x * 32, h0 = blockIdx.y * 256, tid = threadIdx.x;
    if (tid < 32) te[tid] = tab[i0 + tid];
    __syncthreads();
    const float s1 = 0.57735026918962576f, s2 = 0.44721359549995794f;
    for (int il = 0; il < 32; il++) {
        unsigned e = te[il];
        float val = 0.f;
        if ((e >> 14) != 3) {
            int seg = e >> 14, u = (e >> 7) & 127, v = e & 127;
            const float* wb; int S; float sc;
            if (seg == 0)      { wb = w0; S = 128; sc = 1.f; }
            else if (seg == 1) { wb = w1; S = 64;  sc = s1; }
            else               { wb = w2; S = 32;  sc = s2; }
            val = sc * (wb[(size_t)(u * S + v) * 1024 + h0 + tid] +
                        wb[(size_t)(v * S + u) * 1024 + h0 + tid]);
        }
        u16 bv = f2bf(val);
        Wsym[(size_t)(i0 + il) * 1024 + h0 + tid] = bv;
        tile[il][tid] = bv;
    }
    __syncthreads();
    union { u16 a[32]; uint4 q[4]; } pk;
#pragma unroll
    for (int il = 0; il < 32; il++) pk.a[il] = tile[il][tid];
    uint4* dst = (uint4*)(Wt + (size_t)(h0 + tid) * NPACK + i0);
#pragma unroll
    for (int q = 0; q < 4; q++) dst[q] = pk.q[q];
}

// ---------------------------------------------------------------- converts
__global__ __launch_bounds__(256) void k_convert(const float* __restrict__ in,
                                                 u16* __restrict__ out, int n4) {
    int i = blockIdx.x * 256 + threadIdx.x;
    if (i >= n4) return;
    float4 v = ((const float4*)in)[i];
    union { u16 a[4]; unsigned long long q; } o;
    o.a[0] = f2bf(v.x); o.a[1] = f2bf(v.y); o.a[2] = f2bf(v.z); o.a[3] = f2bf(v.w);
    ((unsigned long long*)out)[i] = o.q;
}

// out[(c)*ldOut + r] = bf16(in[r*C + c]);  grid = (C/32, R/32)
__global__ __launch_bounds__(256) void k_transpose(const float* __restrict__ in, int R, int C,
                                                   u16* __restrict__ out, int ldOut) {
    __shared__ float tile[32][33];
    int tr0 = blockIdx.y * 32;
    int tc0 = blockIdx.x * 32;
    int lr = threadIdx.x >> 5;
    int lc = threadIdx.x & 31;
#pragma unroll
    for (int i = 0; i < 4; i++) {
        int rr = lr + i * 8;
        tile[rr][lc] = in[(size_t)(tr0 + rr) * C + tc0 + lc];
    }
    __syncthreads();
#pragma unroll
    for (int i = 0; i < 4; i++) {
        int rr = lr + i * 8;
        out[(size_t)(tc0 + rr) * ldOut + tr0 + lc] = f2bf(tile[lc][rr]);
    }
}

// ---------------------------------------------------------------- packed features
__global__ __launch_bounds__(256) void k_features_pack(const float* __restrict__ t,
                                                       const u16* __restrict__ tab,
                                                       u16* __restrict__ P) {
    __shared__ u16 tab_s[NPACK];
    __shared__ float tr[480];
    int b = blockIdx.x, tid = threadIdx.x;
    for (int j = tid; j < NPACK / 8; j += 256)
        ((uint4*)tab_s)[j] = ((const uint4*)tab)[j];
    for (int j = tid; j < 480; j += 256) tr[j] = t[(size_t)b * 480 + j];
    __syncthreads();
    u16* row = P + (size_t)b * NPACK;
    for (int i = tid; i < NPACK; i += 256) {
        unsigned e = tab_s[i];
        float p = 0.f;
        if ((e >> 14) != 3) {
            int seg = e >> 14, u = (e >> 7) & 127, v = e & 127;
            if (seg == 0) p = tr[u] * tr[v];
            else if (seg == 1) {
                const float* x1 = tr + 128;
                p = x1[u*3]*x1[v*3] + x1[u*3+1]*x1[v*3+1] + x1[u*3+2]*x1[v*3+2];
            } else {
                const float* x2 = tr + 320;
#pragma unroll
                for (int m = 0; m < 5; m++) p += x2[u*5+m] * x2[v*5+m];
            }
            if (u == v) p *= 0.5f;
        }
        row[i] = f2bf(p);
    }
}

// ---------------------------------------------------------------- GEMM (NT, BK=64)
// swz 0: 3-D grid (n,m,sk). swz 1: 1-D 1024 = (sk&7) x 16m x 8n (GEMM1).
// swz 2: 1-D 1408 = 8c x (r%11 -> n-group) x (r/11 -> m), members of an
// n-group share blockIdx%8. Cpart!=null -> fp32 split-K partials.
__global__ __launch_bounds__(256) void k_gemm2(const u16* __restrict__ A, int ldA,
                                               const u16* __restrict__ B, int ldB,
                                               int kLen, float scale,
                                               const float* __restrict__ bias,
                                               float* __restrict__ Cf,
                                               u16* __restrict__ Cb, int ldC,
                                               float* __restrict__ Cpart, int Mtot,
                                               int swz) {
    __shared__ u16 As[2][128 * 32];
    __shared__ u16 Bs[2][128 * 32];
    const int tid = threadIdx.x;
    const int wave = tid >> 6, lane = tid & 63;
    const int wm = wave >> 1, wn = wave & 1;
    int nT, mT, z;
    if (swz == 1) {
        int L = blockIdx.x;
        z = L & 7; int r = L >> 3;
        nT = r >> 4; mT = r & 15;
    } else if (swz == 2) {
        int L = blockIdx.x;
        int c = L & 7, r = L >> 3;
        nT = (r % 11) * 8 + c; mT = r / 11; z = 0;
    } else {
        nT = blockIdx.x; mT = blockIdx.y; z = blockIdx.z;
    }
    const int m0 = mT * 128, n0 = nT * 128;
    const size_t kOff = (size_t)z * kLen;

    const u16* aG = A + (size_t)(m0 + wave * 32 + (lane >> 2)) * ldA + kOff + (lane & 3) * 8;
    const u16* bG = B + (size_t)(n0 + wave * 32 + (lane >> 2)) * ldB + kOff + (lane & 3) * 8;
    const size_t aS = (size_t)16 * ldA;
    const size_t bS = (size_t)16 * ldB;
    u16* aL0 = &As[0][(wave * 32) * 32];
    u16* aL1 = &As[0][(wave * 32 + 16) * 32];
    u16* aH0 = &As[1][(wave * 32) * 32];
    u16* aH1 = &As[1][(wave * 32 + 16) * 32];
    u16* bL0 = &Bs[0][(wave * 32) * 32];
    u16* bL1 = &Bs[0][(wave * 32 + 16) * 32];
    u16* bH0 = &Bs[1][(wave * 32) * 32];
    u16* bH1 = &Bs[1][(wave * 32 + 16) * 32];

    f32x4 acc[4][4];
#pragma unroll
    for (int i = 0; i < 4; i++)
#pragma unroll
        for (int j = 0; j < 4; j++) acc[i][j] = (f32x4){0.f, 0.f, 0.f, 0.f};

    const int ml = lane & 15, kq = (lane >> 4) * 8;
    const u16* aRd0 = &As[0][(wm * 64 + ml) * 32 + kq];
    const u16* bRd0 = &Bs[0][(wn * 64 + ml) * 32 + kq];
    const u16* aRd1 = &As[1][(wm * 64 + ml) * 32 + kq];
    const u16* bRd1 = &Bs[1][(wn * 64 + ml) * 32 + kq];

    for (int k = 0; k < kLen; k += 64) {
        GLOAD_LDS16(aG, aL0);
        GLOAD_LDS16(aG + aS, aL1);
        GLOAD_LDS16(aG + 32, aH0);
        GLOAD_LDS16(aG + aS + 32, aH1);
        GLOAD_LDS16(bG, bL0);
        GLOAD_LDS16(bG + bS, bL1);
        GLOAD_LDS16(bG + 32, bH0);
        GLOAD_LDS16(bG + bS + 32, bH1);
        aG += 64; bG += 64;
        __syncthreads();
        {
            bf16x8 af[4], bfv[4];
#pragma unroll
            for (int i = 0; i < 4; i++) af[i]  = *(const bf16x8*)(aRd0 + i * 16 * 32);
#pragma unroll
            for (int j = 0; j < 4; j++) bfv[j] = *(const bf16x8*)(bRd0 + j * 16 * 32);
#pragma unroll
            for (int i = 0; i < 4; i++)
#pragma unroll
                for (int j = 0; j < 4; j++)
                    acc[i][j] = __builtin_amdgcn_mfma_f32_16x16x32_bf16(af[i], bfv[j], acc[i][j], 0, 0, 0);
        }
        {
            bf16x8 af[4], bfv[4];
#pragma unroll
            for (int i = 0; i < 4; i++) af[i]  = *(const bf16x8*)(aRd1 + i * 16 * 32);
#pragma unroll
            for (int j = 0; j < 4; j++) bfv[j] = *(const bf16x8*)(bRd1 + j * 16 * 32);
#pragma unroll
            for (int i = 0; i < 4; i++)
#pragma unroll
                for (int j = 0; j < 4; j++)
                    acc[i][j] = __builtin_amdgcn_mfma_f32_16x16x32_bf16(af[i], bfv[j], acc[i][j], 0, 0, 0);
        }
        __syncthreads();
    }

    const int q = lane >> 4, nl = lane & 15;   // C/D: col=lane&15, row=(lane>>4)*4+reg
    if (Cpart) {
        float* outP = Cpart + (size_t)z * Mtot * ldC;
#pragma unroll
        for (int i = 0; i < 4; i++)
#pragma unroll
            for (int j = 0; j < 4; j++)
#pragma unroll
                for (int reg = 0; reg < 4; reg++) {
                    int row = m0 + wm * 64 + i * 16 + q * 4 + reg;
                    int col = n0 + wn * 64 + j * 16 + nl;
                    outP[(size_t)row * ldC + col] = acc[i][j][reg];
                }
    } else {
#pragma unroll
        for (int i = 0; i < 4; i++)
#pragma unroll
            for (int j = 0; j < 4; j++)
#pragma unroll
                for (int reg = 0; reg < 4; reg++) {
                    int row = m0 + wm * 64 + i * 16 + q * 4 + reg;
                    int col = n0 + wn * 64 + j * 16 + nl;
                    float v = acc[i][j][reg] * scale + (bias ? bias[col] : 0.0f);
                    if (Cf) Cf[(size_t)row * ldC + col] = v;
                    else    Cb[(size_t)row * ldC + col] = f2bf(v);
                }
    }
}

// sum split-K partials + epilogue
__global__ __launch_bounds__(256) void k_reduce(const float* __restrict__ part, size_t stride,
                                                int SK, int total, int N, float scale,
                                                const float* __restrict__ bias,
                                                float* __restrict__ outF, u16* __restrict__ outB) {
    int i = blockIdx.x * 256 + threadIdx.x;
    if (i >= total) return;
    float s = 0.f;
    for (int z = 0; z < SK; z++) s += part[(size_t)z * stride + i];
    float v = s * scale + (bias ? bias[i % N] : 0.0f);
    if (outF) outF[i] = v;
    else      outB[i] = f2bf(v);
}

// ---------------------------------------------------------------- rowwise LN
__device__ __forceinline__ float blockReduce(float v, float* red) {
#pragma unroll
    for (int off = 32; off > 0; off >>= 1) v += __shfl_down(v, off);
    __syncthreads();
    if ((threadIdx.x & 63) == 0) red[threadIdx.x >> 6] = v;
    __syncthreads();
    return red[0] + red[1] + red[2] + red[3];
}

__global__ __launch_bounds__(256) void k_ln_fwd(const float* __restrict__ X, int D,
    const float* __restrict__ g, const float* __restrict__ be,
    float* __restrict__ mu_out, float* __restrict__ r_out,
    u16* __restrict__ a_bf, float* __restrict__ a_f32) {
    __shared__ float red[4];
    int b = blockIdx.x, tid = threadIdx.x;
    const float* x = X + (size_t)b * D;
    int nd = D >> 8;
    float s = 0.f, s2 = 0.f;
    for (int r = 0; r < nd; r++) { float v = x[tid + (r << 8)]; s += v; s2 += v * v; }
    s = blockReduce(s, red);
    s2 = blockReduce(s2, red);
    float mu = s / D;
    float var = s2 / D - mu * mu;
    float rst = rsqrtf(var + 1e-6f);
    if (tid == 0) { mu_out[b] = mu; r_out[b] = rst; }
    for (int r = 0; r < nd; r++) {
        int i = tid + (r << 8);
        float xh = (x[i] - mu) * rst;
        float ln = xh * g[i] + be[i];
        float a = ln / (1.0f + expf(-ln));
        if (a_bf)  a_bf[(size_t)b * D + i] = f2bf(a);
        if (a_f32) a_f32[(size_t)b * D + i] = a;
    }
}

__global__ __launch_bounds__(256) void k_ln_bwd(const float* __restrict__ dup,
    const float* __restrict__ X, const float* __restrict__ mu_in, const float* __restrict__ r_in,
    const float* __restrict__ g, const float* __restrict__ be,
    u16* __restrict__ out_bf, int D) {
    __shared__ float red[4];
    int b = blockIdx.x, tid = threadIdx.x;
    const float* x = X + (size_t)b * D;
    float mu = mu_in[b], rst = r_in[b];
    int nd = D >> 8;
    float w_[4], xh_[4];
    float sw = 0.f, swx = 0.f;
    for (int r = 0; r < nd; r++) {
        int i = tid + (r << 8);
        float xh = (x[i] - mu) * rst;
        float ln = xh * g[i] + be[i];
        float sg = 1.0f / (1.0f + expf(-ln));
        float dsilu = sg * (1.0f + ln * (1.0f - sg));
        float d = dup ? dup[(size_t)b * D + i] : 1.0f;
        float w = g[i] * dsilu * d;
        w_[r] = w; xh_[r] = xh;
        sw += w; swx += w * xh;
    }
    sw = blockReduce(sw, red);
    swx = blockReduce(swx, red);
    float invD = 1.0f / D;
    for (int r = 0; r < nd; r++) {
        int i = tid + (r << 8);
        float dx = rst * (w_[r] - sw * invD - xh_[r] * swx * invD);
        out_bf[(size_t)b * D + i] = f2bf(dx);
    }
}

// ---------------------------------------------------------------- packed contraction
// y[b,:] from packed symmetric Gp[b, i=(u<=v)]: y_u += g x_v, y_v += g x_u
__global__ __launch_bounds__(256) void k_contract_p(const u16* __restrict__ Gp,
                                                    const u16* __restrict__ tab,
                                                    const float* __restrict__ t,
                                                    float* __restrict__ y) {
    __shared__ u16 gp_s[NPACK];
    __shared__ u16 tab_s[NPACK];
    __shared__ float xs[480];
    __shared__ float ys[480];
    int b = blockIdx.x, tid = threadIdx.x;
    const uint4* gsrc = (const uint4*)(Gp + (size_t)b * NPACK);
    for (int j = tid; j < NPACK / 8; j += 256) {
        ((uint4*)gp_s)[j] = gsrc[j];
        ((uint4*)tab_s)[j] = ((const uint4*)tab)[j];
    }
    for (int j = tid; j < 480; j += 256) { xs[j] = t[(size_t)b * 480 + j]; ys[j] = 0.f; }
    __syncthreads();
    for (int i = tid; i < NVALID; i += 256) {
        unsigned e = tab_s[i];
        int seg = e >> 14;
        int u = (e >> 7) & 127, v = e & 127;
        float g = bf2f(gp_s[i]);
        if (seg == 0) {
            atomicAdd(&ys[u], g * xs[v]);
            if (u != v) atomicAdd(&ys[v], g * xs[u]);
        } else if (seg == 1) {
#pragma unroll
            for (int m = 0; m < 3; m++) atomicAdd(&ys[128 + u * 3 + m], g * xs[128 + v * 3 + m]);
            if (u != v) {
#pragma unroll
                for (int m = 0; m < 3; m++) atomicAdd(&ys[128 + v * 3 + m], g * xs[128 + u * 3 + m]);
            }
        } else {
#pragma unroll
            for (int m = 0; m < 5; m++) atomicAdd(&ys[320 + u * 5 + m], g * xs[320 + v * 5 + m]);
            if (u != v) {
#pragma unroll
                for (int m = 0; m < 5; m++) atomicAdd(&ys[320 + v * 5 + m], g * xs[320 + u * 5 + m]);
            }
        }
    }
    __syncthreads();
    for (int j = tid; j < 480; j += 256) y[(size_t)b * 480 + j] = ys[j];
}

// ---------------------------------------------------------------- launch
extern "C" void kernel_launch(void* const* d_in, const int* in_sizes, int n_in,
                              void* d_out, int out_size, void* d_ws, size_t ws_size,
                              hipStream_t stream) {
    const float* t   = (const float*)d_in[0];
    const float* w0  = (const float*)d_in[1];
    const float* w1  = (const float*)d_in[2];
    const float* w2  = (const float*)d_in[3];
    const float* W1  = (const float*)d_in[4];
    const float* b1  = (const float*)d_in[5];
    const float* g1  = (const float*)d_in[6];
    const float* be1 = (const float*)d_in[7];
    const float* W2  = (const float*)d_in[8];
    const float* b2  = (const float*)d_in[9];
    const float* g2  = (const float*)d_in[10];
    const float* be2 = (const float*)d_in[11];

    float* xout = (float*)d_out;                    // 2048*256
    float* yout = xout + (size_t)2048 * 256;        // 2048*480

    char* ws = (char*)d_ws;
    size_t off = 0;
    auto alloc = [&](size_t bytes) -> void* {
        void* p = ws + off;
        off += (bytes + 255) & ~(size_t)255;
        return p;
    };
    u16*   PG    = (u16*)alloc((size_t)2048 * NPACK * 2);   // Ppack, later Gp (aliased)
    u16*   Wsym  = (u16*)alloc((size_t)NPACK * 1024 * 2);   // packed Wsym [i,h]
    u16*   Wt    = (u16*)alloc((size_t)1024 * NPACK * 2);   // packed Wsym^T [h,i]
    u16*   uvtab = (u16*)alloc((size_t)NPACK * 2);
    u16*   W1b   = (u16*)alloc((size_t)1024 * 1024 * 2);
    u16*   W1tb  = (u16*)alloc((size_t)1024 * 1024 * 2);
    u16*   W2b   = (u16*)alloc((size_t)1024 * 256 * 2);
    u16*   W2tb  = (u16*)alloc((size_t)256 * 1024 * 2);
    u16*   h_bf  = (u16*)alloc((size_t)2048 * 1024 * 2);
    float* h1pre = (float*)alloc((size_t)2048 * 1024 * 4);
    float* mu1   = (float*)alloc(2048 * 4);
    float* r1    = (float*)alloc(2048 * 4);
    u16*   a1_bf = (u16*)alloc((size_t)2048 * 1024 * 2);
    float* h2pre = (float*)alloc((size_t)2048 * 256 * 4);
    float* mu2   = (float*)alloc(2048 * 4);
    float* r2    = (float*)alloc(2048 * 4);
    u16*   dh2b  = (u16*)alloc((size_t)2048 * 256 * 2);
    float* d_a1  = (float*)alloc((size_t)2048 * 1024 * 4);
    u16*   dh1b  = (u16*)alloc((size_t)2048 * 1024 * 2);
    u16*   de_bf = (u16*)alloc((size_t)2048 * 1024 * 2);
    float* Cpart = (float*)(ws + off);
    size_t cpartBytes = (ws_size > off) ? (ws_size - off) : 0;
    (void)in_sizes; (void)n_in; (void)out_size;

    const float sF = 1.0f / sqrtf(21504.0f);

    // generic GEMM helper (MLP GEMMs): 3-D grid, optional split-K
    auto gemm = [&](const u16* A, int ldA, const u16* B, int ldB, int M, int N, int K,
                    int SKwant, float scale, const float* bias,
                    float* Cf, u16* Cb, int ldC) {
        int SK = SKwant;
        size_t slice = (size_t)M * ldC * 4;
        if (SK > 1 && cpartBytes < 2 * slice) SK = 1;
        if (SK > 1 && (size_t)SK * slice > cpartBytes) SK = (int)(cpartBytes / slice);
        while (SK > 1 && !((K % SK) == 0 && ((K / SK) % 64) == 0)) SK--;
        dim3 grid(N / 128, M / 128, SK);
        if (SK > 1) {
            k_gemm2<<<grid, 256, 0, stream>>>(A, ldA, B, ldB, K / SK, 0.f, nullptr,
                                              nullptr, nullptr, ldC, Cpart, M, 0);
            int total = M * ldC;
            k_reduce<<<(total + 255) / 256, 256, 0, stream>>>(Cpart, (size_t)M * ldC, SK,
                                                              total, N, scale, bias, Cf, Cb);
        } else {
            k_gemm2<<<grid, 256, 0, stream>>>(A, ldA, B, ldB, K, scale, bias,
                                              Cf, Cb, ldC, nullptr, M, 0);
        }
    };

    // index table + packed weights
    k_uv<<<64, 256, 0, stream>>>(128, 7, 0, 0, uvtab);
    k_uv<<<16, 256, 0, stream>>>(64, 6, BASE1, 1, uvtab);
    k_uv<<<4, 256, 0, stream>>>(32, 5, BASE2, 2, uvtab);
    k_uvpad<<<2, 256, 0, stream>>>(uvtab);
    k_packw<<<dim3(NPACK / 32, 4), 256, 0, stream>>>(w0, w1, w2, uvtab, Wsym, Wt);

    // small MLP weights
    k_transpose<<<dim3(32, 32), 256, 0, stream>>>(W1, 1024, 1024, W1tb, 1024);
    k_transpose<<<dim3(8, 32), 256, 0, stream>>>(W2, 1024, 256, W2tb, 1024);
    k_convert<<<1024 * 1024 / 1024, 256, 0, stream>>>(W1, W1b, 1024 * 1024 / 4);
    k_convert<<<1024 * 256 / 1024, 256, 0, stream>>>(W2, W2b, 1024 * 256 / 4);

    // packed features
    k_features_pack<<<2048, 256, 0, stream>>>(t, uvtab, PG);

    // h = sF * Ppack @ Wt^T : K=11264, SK=8 (kLen=1408), XCD-swizzled 1024 blocks
    k_gemm2<<<dim3(1024), 256, 0, stream>>>(PG, NPACK, Wt, NPACK, NPACK / 8, 0.f, nullptr,
                                            nullptr, nullptr, 1024, Cpart, 2048, 1);
    {
        int total = 2048 * 1024;
        k_reduce<<<(total + 255) / 256, 256, 0, stream>>>(Cpart, (size_t)2048 * 1024, 8,
                                                          total, 1024, sF, nullptr,
                                                          nullptr, h_bf);
    }

    // MLP forward
    gemm(h_bf, 1024, W1tb, 1024, 2048, 1024, 1024, 4, 1.0f, b1, h1pre, nullptr, 1024);
    k_ln_fwd<<<2048, 256, 0, stream>>>(h1pre, 1024, g1, be1, mu1, r1, a1_bf, nullptr);
    gemm(a1_bf, 1024, W2tb, 1024, 2048, 256, 1024, 8, 1.0f, b2, h2pre, nullptr, 256);
    k_ln_fwd<<<2048, 256, 0, stream>>>(h2pre, 256, g2, be2, mu2, r2, nullptr, xout);

    // backward
    k_ln_bwd<<<2048, 256, 0, stream>>>(nullptr, h2pre, mu2, r2, g2, be2, dh2b, 256);
    gemm(dh2b, 256, W2b, 256, 2048, 1024, 256, 4, 1.0f, nullptr, d_a1, nullptr, 1024);
    k_ln_bwd<<<2048, 256, 0, stream>>>(d_a1, h1pre, mu1, r1, g1, be1, dh1b, 1024);
    gemm(dh1b, 1024, W1b, 1024, 2048, 1024, 1024, 4, sF, nullptr, nullptr, de_bf, 1024);

    // Gp = de @ Wsym^T (packed N=11264): 1408 blocks, grouped swizzle, bf16 out
    u16* Gp = PG;   // Ppack dead after GEMM1
    k_gemm2<<<dim3(1408), 256, 0, stream>>>(de_bf, 1024, Wsym, 1024, 1024, 1.0f, nullptr,
                                            nullptr, Gp, NPACK, nullptr, 2048, 2);

    // y from packed symmetric Gp
    k_contract_p<<<2048, 256, 0, stream>>>(Gp, uvtab, t, yout);
}

// Round 7
// 526.583 us; speedup vs baseline: 1.6365x; 1.6365x over previous
//
#include <hip/hip_runtime.h>
#include <math.h>

typedef unsigned short u16;
typedef __bf16 bf16x8 __attribute__((ext_vector_type(8)));
typedef float f32x4 __attribute__((ext_vector_type(4)));

#define NPACK  11264   // padded packed-pair count (88*128)
#define NVALID 10864   // 8256 + 2080 + 528
#define BASE1  8256
#define BASE2  10336

__device__ __forceinline__ u16 f2bf(float f) {
    unsigned u = __builtin_bit_cast(unsigned, f);
    u += 0x7FFFu + ((u >> 16) & 1u);
    return (u16)(u >> 16);
}
__device__ __forceinline__ float bf2f(u16 h) {
    return __builtin_bit_cast(float, ((unsigned)h) << 16);
}

#define GLOAD_LDS16(g, l)                                                     \
    __builtin_amdgcn_global_load_lds(                                         \
        (const __attribute__((address_space(1))) void*)(g),                   \
        (__attribute__((address_space(3))) void*)(l), 16, 0, 0)

// packed triangular index (u<=v), per segment
__device__ __forceinline__ int pk0(int a, int b) {
    int u = min(a, b), v = max(a, b);
    return u * 128 - (u * (u - 1)) / 2 + (v - u);
}
__device__ __forceinline__ int pk1(int a, int b) {
    int u = min(a, b), v = max(a, b);
    return BASE1 + u * 64 - (u * (u - 1)) / 2 + (v - u);
}
__device__ __forceinline__ int pk2(int a, int b) {
    int u = min(a, b), v = max(a, b);
    return BASE2 + u * 32 - (u * (u - 1)) / 2 + (v - u);
}

// ---------------------------------------------------------------- uv table
// tab[i] = seg<<14 | u<<7 | v   for packed triangular index i (u<=v)
__global__ __launch_bounds__(256) void k_uv(int S, int lg, int base, int seg,
                                            u16* __restrict__ tab) {
    int j = blockIdx.x * 256 + threadIdx.x;
    int u = j >> lg, v = j & (S - 1);
    if (u >= S || v < u) return;
    int i = base + u * S - (u * (u - 1)) / 2 + (v - u);
    tab[i] = (u16)((seg << 14) | (u << 7) | v);
}
__global__ __launch_bounds__(256) void k_uvpad(u16* __restrict__ tab) {
    int j = blockIdx.x * 256 + threadIdx.x;
    if (NVALID + j < NPACK) tab[NVALID + j] = 0xFFFFu;
}

// ---------------------------------------------------------------- packed weights
// Wsym[i,h] = s_seg*(w[uv,h]+w[vu,h])  (diag -> 2w, features carry the 0.5)
// Wt[h,i]   = same values transposed (K-contiguous for GEMM1's B operand)
__global__ __launch_bounds__(256) void k_packw(const float* __restrict__ w0,
                                               const float* __restrict__ w1,
                                               const float* __restrict__ w2,
                                               const u16* __restrict__ tab,
                                               u16* __restrict__ Wsym,
                                               u16* __restrict__ Wt) {
    __shared__ u16 tile[32][258];
    __shared__ u16 te[32];
    int i0 = blockIdx.x * 32, h0 = blockIdx.y * 256, tid = threadIdx.x;
    if (tid < 32) te[tid] = tab[i0 + tid];
    __syncthreads();
    const float s1 = 0.57735026918962576f, s2 = 0.44721359549995794f;
    for (int il = 0; il < 32; il++) {
        unsigned e = te[il];
        float val = 0.f;
        if ((e >> 14) != 3) {
            int seg = e >> 14, u = (e >> 7) & 127, v = e & 127;
            const float* wb; int S; float sc;
            if (seg == 0)      { wb = w0; S = 128; sc = 1.f; }
            else if (seg == 1) { wb = w1; S = 64;  sc = s1; }
            else               { wb = w2; S = 32;  sc = s2; }
            val = sc * (wb[(size_t)(u * S + v) * 1024 + h0 + tid] +
                        wb[(size_t)(v * S + u) * 1024 + h0 + tid]);
        }
        u16 bv = f2bf(val);
        Wsym[(size_t)(i0 + il) * 1024 + h0 + tid] = bv;
        tile[il][tid] = bv;
    }
    __syncthreads();
    union { u16 a[32]; uint4 q[4]; } pk;
#pragma unroll
    for (int il = 0; il < 32; il++) pk.a[il] = tile[il][tid];
    uint4* dst = (uint4*)(Wt + (size_t)(h0 + tid) * NPACK + i0);
#pragma unroll
    for (int q = 0; q < 4; q++) dst[q] = pk.q[q];
}

// ---------------------------------------------------------------- converts
__global__ __launch_bounds__(256) void k_convert(const float* __restrict__ in,
                                                 u16* __restrict__ out, int n4) {
    int i = blockIdx.x * 256 + threadIdx.x;
    if (i >= n4) return;
    float4 v = ((const float4*)in)[i];
    union { u16 a[4]; unsigned long long q; } o;
    o.a[0] = f2bf(v.x); o.a[1] = f2bf(v.y); o.a[2] = f2bf(v.z); o.a[3] = f2bf(v.w);
    ((unsigned long long*)out)[i] = o.q;
}

// out[(c)*ldOut + r] = bf16(in[r*C + c]);  grid = (C/32, R/32)
__global__ __launch_bounds__(256) void k_transpose(const float* __restrict__ in, int R, int C,
                                                   u16* __restrict__ out, int ldOut) {
    __shared__ float tile[32][33];
    int tr0 = blockIdx.y * 32;
    int tc0 = blockIdx.x * 32;
    int lr = threadIdx.x >> 5;
    int lc = threadIdx.x & 31;
#pragma unroll
    for (int i = 0; i < 4; i++) {
        int rr = lr + i * 8;
        tile[rr][lc] = in[(size_t)(tr0 + rr) * C + tc0 + lc];
    }
    __syncthreads();
#pragma unroll
    for (int i = 0; i < 4; i++) {
        int rr = lr + i * 8;
        out[(size_t)(tc0 + rr) * ldOut + tr0 + lc] = f2bf(tile[lc][rr]);
    }
}

// ---------------------------------------------------------------- packed features
__global__ __launch_bounds__(256) void k_features_pack(const float* __restrict__ t,
                                                       const u16* __restrict__ tab,
                                                       u16* __restrict__ P) {
    __shared__ u16 tab_s[NPACK];
    __shared__ float tr[480];
    int b = blockIdx.x, tid = threadIdx.x;
    for (int j = tid; j < NPACK / 8; j += 256)
        ((uint4*)tab_s)[j] = ((const uint4*)tab)[j];
    for (int j = tid; j < 480; j += 256) tr[j] = t[(size_t)b * 480 + j];
    __syncthreads();
    u16* row = P + (size_t)b * NPACK;
    for (int i = tid; i < NPACK; i += 256) {
        unsigned e = tab_s[i];
        float p = 0.f;
        if ((e >> 14) != 3) {
            int seg = e >> 14, u = (e >> 7) & 127, v = e & 127;
            if (seg == 0) p = tr[u] * tr[v];
            else if (seg == 1) {
                const float* x1 = tr + 128;
                p = x1[u*3]*x1[v*3] + x1[u*3+1]*x1[v*3+1] + x1[u*3+2]*x1[v*3+2];
            } else {
                const float* x2 = tr + 320;
#pragma unroll
                for (int m = 0; m < 5; m++) p += x2[u*5+m] * x2[v*5+m];
            }
            if (u == v) p *= 0.5f;
        }
        row[i] = f2bf(p);
    }
}

// ---------------------------------------------------------------- GEMM (NT, BK=64)
// swz 0: 3-D grid (n,m,sk). swz 1: 1-D 1024 = (sk&7) x 16m x 8n (GEMM1).
// swz 2: 1-D 1408 = 8c x (r%11 -> n-group) x (r/11 -> m), members of an
// n-group share blockIdx%8. Cpart!=null -> fp32 split-K partials.
__global__ __launch_bounds__(256) void k_gemm2(const u16* __restrict__ A, int ldA,
                                               const u16* __restrict__ B, int ldB,
                                               int kLen, float scale,
                                               const float* __restrict__ bias,
                                               float* __restrict__ Cf,
                                               u16* __restrict__ Cb, int ldC,
                                               float* __restrict__ Cpart, int Mtot,
                                               int swz) {
    __shared__ u16 As[2][128 * 32];
    __shared__ u16 Bs[2][128 * 32];
    const int tid = threadIdx.x;
    const int wave = tid >> 6, lane = tid & 63;
    const int wm = wave >> 1, wn = wave & 1;
    int nT, mT, z;
    if (swz == 1) {
        int L = blockIdx.x;
        z = L & 7; int r = L >> 3;
        nT = r >> 4; mT = r & 15;
    } else if (swz == 2) {
        int L = blockIdx.x;
        int c = L & 7, r = L >> 3;
        nT = (r % 11) * 8 + c; mT = r / 11; z = 0;
    } else {
        nT = blockIdx.x; mT = blockIdx.y; z = blockIdx.z;
    }
    const int m0 = mT * 128, n0 = nT * 128;
    const size_t kOff = (size_t)z * kLen;

    const u16* aG = A + (size_t)(m0 + wave * 32 + (lane >> 2)) * ldA + kOff + (lane & 3) * 8;
    const u16* bG = B + (size_t)(n0 + wave * 32 + (lane >> 2)) * ldB + kOff + (lane & 3) * 8;
    const size_t aS = (size_t)16 * ldA;
    const size_t bS = (size_t)16 * ldB;
    u16* aL0 = &As[0][(wave * 32) * 32];
    u16* aL1 = &As[0][(wave * 32 + 16) * 32];
    u16* aH0 = &As[1][(wave * 32) * 32];
    u16* aH1 = &As[1][(wave * 32 + 16) * 32];
    u16* bL0 = &Bs[0][(wave * 32) * 32];
    u16* bL1 = &Bs[0][(wave * 32 + 16) * 32];
    u16* bH0 = &Bs[1][(wave * 32) * 32];
    u16* bH1 = &Bs[1][(wave * 32 + 16) * 32];

    f32x4 acc[4][4];
#pragma unroll
    for (int i = 0; i < 4; i++)
#pragma unroll
        for (int j = 0; j < 4; j++) acc[i][j] = (f32x4){0.f, 0.f, 0.f, 0.f};

    const int ml = lane & 15, kq = (lane >> 4) * 8;
    const u16* aRd0 = &As[0][(wm * 64 + ml) * 32 + kq];
    const u16* bRd0 = &Bs[0][(wn * 64 + ml) * 32 + kq];
    const u16* aRd1 = &As[1][(wm * 64 + ml) * 32 + kq];
    const u16* bRd1 = &Bs[1][(wn * 64 + ml) * 32 + kq];

    for (int k = 0; k < kLen; k += 64) {
        GLOAD_LDS16(aG, aL0);
        GLOAD_LDS16(aG + aS, aL1);
        GLOAD_LDS16(aG + 32, aH0);
        GLOAD_LDS16(aG + aS + 32, aH1);
        GLOAD_LDS16(bG, bL0);
        GLOAD_LDS16(bG + bS, bL1);
        GLOAD_LDS16(bG + 32, bH0);
        GLOAD_LDS16(bG + bS + 32, bH1);
        aG += 64; bG += 64;
        __syncthreads();
        {
            bf16x8 af[4], bfv[4];
#pragma unroll
            for (int i = 0; i < 4; i++) af[i]  = *(const bf16x8*)(aRd0 + i * 16 * 32);
#pragma unroll
            for (int j = 0; j < 4; j++) bfv[j] = *(const bf16x8*)(bRd0 + j * 16 * 32);
#pragma unroll
            for (int i = 0; i < 4; i++)
#pragma unroll
                for (int j = 0; j < 4; j++)
                    acc[i][j] = __builtin_amdgcn_mfma_f32_16x16x32_bf16(af[i], bfv[j], acc[i][j], 0, 0, 0);
        }
        {
            bf16x8 af[4], bfv[4];
#pragma unroll
            for (int i = 0; i < 4; i++) af[i]  = *(const bf16x8*)(aRd1 + i * 16 * 32);
#pragma unroll
            for (int j = 0; j < 4; j++) bfv[j] = *(const bf16x8*)(bRd1 + j * 16 * 32);
#pragma unroll
            for (int i = 0; i < 4; i++)
#pragma unroll
                for (int j = 0; j < 4; j++)
                    acc[i][j] = __builtin_amdgcn_mfma_f32_16x16x32_bf16(af[i], bfv[j], acc[i][j], 0, 0, 0);
        }
        __syncthreads();
    }

    const int q = lane >> 4, nl = lane & 15;   // C/D: col=lane&15, row=(lane>>4)*4+reg
    if (Cpart) {
        float* outP = Cpart + (size_t)z * Mtot * ldC;
#pragma unroll
        for (int i = 0; i < 4; i++)
#pragma unroll
            for (int j = 0; j < 4; j++)
#pragma unroll
                for (int reg = 0; reg < 4; reg++) {
                    int row = m0 + wm * 64 + i * 16 + q * 4 + reg;
                    int col = n0 + wn * 64 + j * 16 + nl;
                    outP[(size_t)row * ldC + col] = acc[i][j][reg];
                }
    } else {
#pragma unroll
        for (int i = 0; i < 4; i++)
#pragma unroll
            for (int j = 0; j < 4; j++)
#pragma unroll
                for (int reg = 0; reg < 4; reg++) {
                    int row = m0 + wm * 64 + i * 16 + q * 4 + reg;
                    int col = n0 + wn * 64 + j * 16 + nl;
                    float v = acc[i][j][reg] * scale + (bias ? bias[col] : 0.0f);
                    if (Cf) Cf[(size_t)row * ldC + col] = v;
                    else    Cb[(size_t)row * ldC + col] = f2bf(v);
                }
    }
}

// sum split-K partials + epilogue
__global__ __launch_bounds__(256) void k_reduce(const float* __restrict__ part, size_t stride,
                                                int SK, int total, int N, float scale,
                                                const float* __restrict__ bias,
                                                float* __restrict__ outF, u16* __restrict__ outB) {
    int i = blockIdx.x * 256 + threadIdx.x;
    if (i >= total) return;
    float s = 0.f;
    for (int z = 0; z < SK; z++) s += part[(size_t)z * stride + i];
    float v = s * scale + (bias ? bias[i % N] : 0.0f);
    if (outF) outF[i] = v;
    else      outB[i] = f2bf(v);
}

// ---------------------------------------------------------------- rowwise LN
__device__ __forceinline__ float blockReduce(float v, float* red) {
#pragma unroll
    for (int off = 32; off > 0; off >>= 1) v += __shfl_down(v, off);
    __syncthreads();
    if ((threadIdx.x & 63) == 0) red[threadIdx.x >> 6] = v;
    __syncthreads();
    return red[0] + red[1] + red[2] + red[3];
}

__global__ __launch_bounds__(256) void k_ln_fwd(const float* __restrict__ X, int D,
    const float* __restrict__ g, const float* __restrict__ be,
    float* __restrict__ mu_out, float* __restrict__ r_out,
    u16* __restrict__ a_bf, float* __restrict__ a_f32) {
    __shared__ float red[4];
    int b = blockIdx.x, tid = threadIdx.x;
    const float* x = X + (size_t)b * D;
    int nd = D >> 8;
    float s = 0.f, s2 = 0.f;
    for (int r = 0; r < nd; r++) { float v = x[tid + (r << 8)]; s += v; s2 += v * v; }
    s = blockReduce(s, red);
    s2 = blockReduce(s2, red);
    float mu = s / D;
    float var = s2 / D - mu * mu;
    float rst = rsqrtf(var + 1e-6f);
    if (tid == 0) { mu_out[b] = mu; r_out[b] = rst; }
    for (int r = 0; r < nd; r++) {
        int i = tid + (r << 8);
        float xh = (x[i] - mu) * rst;
        float ln = xh * g[i] + be[i];
        float a = ln / (1.0f + expf(-ln));
        if (a_bf)  a_bf[(size_t)b * D + i] = f2bf(a);
        if (a_f32) a_f32[(size_t)b * D + i] = a;
    }
}

__global__ __launch_bounds__(256) void k_ln_bwd(const float* __restrict__ dup,
    const float* __restrict__ X, const float* __restrict__ mu_in, const float* __restrict__ r_in,
    const float* __restrict__ g, const float* __restrict__ be,
    u16* __restrict__ out_bf, int D) {
    __shared__ float red[4];
    int b = blockIdx.x, tid = threadIdx.x;
    const float* x = X + (size_t)b * D;
    float mu = mu_in[b], rst = r_in[b];
    int nd = D >> 8;
    float w_[4], xh_[4];
    float sw = 0.f, swx = 0.f;
    for (int r = 0; r < nd; r++) {
        int i = tid + (r << 8);
        float xh = (x[i] - mu) * rst;
        float ln = xh * g[i] + be[i];
        float sg = 1.0f / (1.0f + expf(-ln));
        float dsilu = sg * (1.0f + ln * (1.0f - sg));
        float d = dup ? dup[(size_t)b * D + i] : 1.0f;
        float w = g[i] * dsilu * d;
        w_[r] = w; xh_[r] = xh;
        sw += w; swx += w * xh;
    }
    sw = blockReduce(sw, red);
    swx = blockReduce(swx, red);
    float invD = 1.0f / D;
    for (int r = 0; r < nd; r++) {
        int i = tid + (r << 8);
        float dx = rst * (w_[r] - sw * invD - xh_[r] * swx * invD);
        out_bf[(size_t)b * D + i] = f2bf(dx);
    }
}

// ---------------------------------------------------------------- packed contraction
// y[b,a] = sum_v Gsym[a,v] x[v],  Gsym[a,v] = Gp[pack(a,v)] (scales folded into Wsym).
// Shuffle-reduce row dots, no atomics.
__global__ __launch_bounds__(256) void k_contract_p(const u16* __restrict__ Gp,
                                                    const float* __restrict__ t,
                                                    float* __restrict__ y) {
    __shared__ u16 gp_s[NPACK];
    __shared__ float xs[480];
    int b = blockIdx.x, tid = threadIdx.x;
    const uint4* gsrc = (const uint4*)(Gp + (size_t)b * NPACK);
    for (int j = tid; j < NPACK / 8; j += 256) ((uint4*)gp_s)[j] = gsrc[j];
    for (int j = tid; j < 480; j += 256) xs[j] = t[(size_t)b * 480 + j];
    __syncthreads();
    int wave = tid >> 6, lane = tid & 63;
    float* yr = y + (size_t)b * 480;
    // seg0: 128 outputs; wave handles 32 rows; lane covers v=lane and v=lane+64
    for (int r = 0; r < 32; r++) {
        int u = wave * 32 + r;
        int v0 = lane, v1 = lane + 64;
        float s = bf2f(gp_s[pk0(u, v0)]) * xs[v0] + bf2f(gp_s[pk0(u, v1)]) * xs[v1];
#pragma unroll
        for (int off = 32; off > 0; off >>= 1) s += __shfl_down(s, off);
        if (lane == 0) yr[u] = s;
    }
    // seg1: 64 u x 3 m; wave handles 16 u; lane = v
    for (int r = 0; r < 16; r++) {
        int u = wave * 16 + r;
        float gv = bf2f(gp_s[pk1(u, lane)]);
        float a0 = gv * xs[128 + lane * 3 + 0];
        float a1 = gv * xs[128 + lane * 3 + 1];
        float a2 = gv * xs[128 + lane * 3 + 2];
#pragma unroll
        for (int off = 32; off > 0; off >>= 1) {
            a0 += __shfl_down(a0, off);
            a1 += __shfl_down(a1, off);
            a2 += __shfl_down(a2, off);
        }
        if (lane == 0) {
            yr[128 + u * 3 + 0] = a0;
            yr[128 + u * 3 + 1] = a1;
            yr[128 + u * 3 + 2] = a2;
        }
    }
    // seg2: 32 u x 5 m; wave handles 8 u; lanes 0..31 = v
    for (int r = 0; r < 8; r++) {
        int u = wave * 8 + r;
        bool act = lane < 32;
        float gv = act ? bf2f(gp_s[pk2(u, act ? lane : 0)]) : 0.f;
        float a[5];
#pragma unroll
        for (int m = 0; m < 5; m++)
            a[m] = act ? gv * xs[320 + lane * 5 + m] : 0.f;
#pragma unroll
        for (int off = 32; off > 0; off >>= 1)
#pragma unroll
            for (int m = 0; m < 5; m++) a[m] += __shfl_down(a[m], off);
        if (lane == 0)
#pragma unroll
            for (int m = 0; m < 5; m++) yr[320 + u * 5 + m] = a[m];
    }
}

// ---------------------------------------------------------------- launch
extern "C" void kernel_launch(void* const* d_in, const int* in_sizes, int n_in,
                              void* d_out, int out_size, void* d_ws, size_t ws_size,
                              hipStream_t stream) {
    const float* t   = (const float*)d_in[0];
    const float* w0  = (const float*)d_in[1];
    const float* w1  = (const float*)d_in[2];
    const float* w2  = (const float*)d_in[3];
    const float* W1  = (const float*)d_in[4];
    const float* b1  = (const float*)d_in[5];
    const float* g1  = (const float*)d_in[6];
    const float* be1 = (const float*)d_in[7];
    const float* W2  = (const float*)d_in[8];
    const float* b2  = (const float*)d_in[9];
    const float* g2  = (const float*)d_in[10];
    const float* be2 = (const float*)d_in[11];

    float* xout = (float*)d_out;                    // 2048*256
    float* yout = xout + (size_t)2048 * 256;        // 2048*480

    char* ws = (char*)d_ws;
    size_t off = 0;
    auto alloc = [&](size_t bytes) -> void* {
        void* p = ws + off;
        off += (bytes + 255) & ~(size_t)255;
        return p;
    };
    u16*   PG    = (u16*)alloc((size_t)2048 * NPACK * 2);   // Ppack, later Gp (aliased)
    u16*   Wsym  = (u16*)alloc((size_t)NPACK * 1024 * 2);   // packed Wsym [i,h]
    u16*   Wt    = (u16*)alloc((size_t)1024 * NPACK * 2);   // packed Wsym^T [h,i]
    u16*   uvtab = (u16*)alloc((size_t)NPACK * 2);
    u16*   W1b   = (u16*)alloc((size_t)1024 * 1024 * 2);
    u16*   W1tb  = (u16*)alloc((size_t)1024 * 1024 * 2);
    u16*   W2b   = (u16*)alloc((size_t)1024 * 256 * 2);
    u16*   W2tb  = (u16*)alloc((size_t)256 * 1024 * 2);
    u16*   h_bf  = (u16*)alloc((size_t)2048 * 1024 * 2);
    float* h1pre = (float*)alloc((size_t)2048 * 1024 * 4);
    float* mu1   = (float*)alloc(2048 * 4);
    float* r1    = (float*)alloc(2048 * 4);
    u16*   a1_bf = (u16*)alloc((size_t)2048 * 1024 * 2);
    float* h2pre = (float*)alloc((size_t)2048 * 256 * 4);
    float* mu2   = (float*)alloc(2048 * 4);
    float* r2    = (float*)alloc(2048 * 4);
    u16*   dh2b  = (u16*)alloc((size_t)2048 * 256 * 2);
    float* d_a1  = (float*)alloc((size_t)2048 * 1024 * 4);
    u16*   dh1b  = (u16*)alloc((size_t)2048 * 1024 * 2);
    u16*   de_bf = (u16*)alloc((size_t)2048 * 1024 * 2);
    float* Cpart = (float*)(ws + off);
    size_t cpartBytes = (ws_size > off) ? (ws_size - off) : 0;
    (void)in_sizes; (void)n_in; (void)out_size;

    const float sF = 1.0f / sqrtf(21504.0f);

    // generic GEMM helper (MLP GEMMs): 3-D grid, optional split-K
    auto gemm = [&](const u16* A, int ldA, const u16* B, int ldB, int M, int N, int K,
                    int SKwant, float scale, const float* bias,
                    float* Cf, u16* Cb, int ldC) {
        int SK = SKwant;
        size_t slice = (size_t)M * ldC * 4;
        if (SK > 1 && cpartBytes < 2 * slice) SK = 1;
        if (SK > 1 && (size_t)SK * slice > cpartBytes) SK = (int)(cpartBytes / slice);
        while (SK > 1 && !((K % SK) == 0 && ((K / SK) % 64) == 0)) SK--;
        dim3 grid(N / 128, M / 128, SK);
        if (SK > 1) {
            k_gemm2<<<grid, 256, 0, stream>>>(A, ldA, B, ldB, K / SK, 0.f, nullptr,
                                              nullptr, nullptr, ldC, Cpart, M, 0);
            int total = M * ldC;
            k_reduce<<<(total + 255) / 256, 256, 0, stream>>>(Cpart, (size_t)M * ldC, SK,
                                                              total, N, scale, bias, Cf, Cb);
        } else {
            k_gemm2<<<grid, 256, 0, stream>>>(A, ldA, B, ldB, K, scale, bias,
                                              Cf, Cb, ldC, nullptr, M, 0);
        }
    };

    // index table + packed weights
    k_uv<<<64, 256, 0, stream>>>(128, 7, 0, 0, uvtab);
    k_uv<<<16, 256, 0, stream>>>(64, 6, BASE1, 1, uvtab);
    k_uv<<<4, 256, 0, stream>>>(32, 5, BASE2, 2, uvtab);
    k_uvpad<<<2, 256, 0, stream>>>(uvtab);
    k_packw<<<dim3(NPACK / 32, 4), 256, 0, stream>>>(w0, w1, w2, uvtab, Wsym, Wt);

    // small MLP weights
    k_transpose<<<dim3(32, 32), 256, 0, stream>>>(W1, 1024, 1024, W1tb, 1024);
    k_transpose<<<dim3(8, 32), 256, 0, stream>>>(W2, 1024, 256, W2tb, 1024);
    k_convert<<<1024 * 1024 / 1024, 256, 0, stream>>>(W1, W1b, 1024 * 1024 / 4);
    k_convert<<<1024 * 256 / 1024, 256, 0, stream>>>(W2, W2b, 1024 * 256 / 4);

    // packed features
    k_features_pack<<<2048, 256, 0, stream>>>(t, uvtab, PG);

    // h = sF * Ppack @ Wt^T : K=11264, SK=8 (kLen=1408), XCD-swizzled 1024 blocks
    k_gemm2<<<dim3(1024), 256, 0, stream>>>(PG, NPACK, Wt, NPACK, NPACK / 8, 0.f, nullptr,
                                            nullptr, nullptr, 1024, Cpart, 2048, 1);
    {
        int total = 2048 * 1024;
        k_reduce<<<(total + 255) / 256, 256, 0, stream>>>(Cpart, (size_t)2048 * 1024, 8,
                                                          total, 1024, sF, nullptr,
                                                          nullptr, h_bf);
    }

    // MLP forward
    gemm(h_bf, 1024, W1tb, 1024, 2048, 1024, 1024, 4, 1.0f, b1, h1pre, nullptr, 1024);
    k_ln_fwd<<<2048, 256, 0, stream>>>(h1pre, 1024, g1, be1, mu1, r1, a1_bf, nullptr);
    gemm(a1_bf, 1024, W2tb, 1024, 2048, 256, 1024, 8, 1.0f, b2, h2pre, nullptr, 256);
    k_ln_fwd<<<2048, 256, 0, stream>>>(h2pre, 256, g2, be2, mu2, r2, nullptr, xout);

    // backward
    k_ln_bwd<<<2048, 256, 0, stream>>>(nullptr, h2pre, mu2, r2, g2, be2, dh2b, 256);
    gemm(dh2b, 256, W2b, 256, 2048, 1024, 256, 4, 1.0f, nullptr, d_a1, nullptr, 1024);
    k_ln_bwd<<<2048, 256, 0, stream>>>(d_a1, h1pre, mu1, r1, g1, be1, dh1b, 1024);
    gemm(dh1b, 1024, W1b, 1024, 2048, 1024, 1024, 4, sF, nullptr, nullptr, de_bf, 1024);

    // Gp = de @ Wsym^T (packed N=11264): 1408 blocks, grouped swizzle, bf16 out
    u16* Gp = PG;   // Ppack dead after GEMM1
    k_gemm2<<<dim3(1408), 256, 0, stream>>>(de_bf, 1024, Wsym, 1024, 1024, 1.0f, nullptr,
                                            nullptr, Gp, NPACK, nullptr, 2048, 2);

    // y from packed symmetric Gp (shuffle-reduce, no atomics)
    k_contract_p<<<2048, 256, 0, stream>>>(Gp, t, yout);
}

// Round 8
// 517.732 us; speedup vs baseline: 1.6644x; 1.0171x over previous
//
#include <hip/hip_runtime.h>
#include <math.h>

typedef unsigned short u16;
typedef __bf16 bf16x8 __attribute__((ext_vector_type(8)));
typedef float f32x4 __attribute__((ext_vector_type(4)));

#define NPACK  11264   // padded packed-pair count (88*128)
#define NVALID 10864   // 8256 + 2080 + 528
#define BASE1  8256
#define BASE2  10336

__device__ __forceinline__ u16 f2bf(float f) {
    unsigned u = __builtin_bit_cast(unsigned, f);
    u += 0x7FFFu + ((u >> 16) & 1u);
    return (u16)(u >> 16);
}
__device__ __forceinline__ float bf2f(u16 h) {
    return __builtin_bit_cast(float, ((unsigned)h) << 16);
}

#define GLOAD_LDS16(g, l)                                                     \
    __builtin_amdgcn_global_load_lds(                                         \
        (const __attribute__((address_space(1))) void*)(g),                   \
        (__attribute__((address_space(3))) void*)(l), 16, 0, 0)

// packed triangular index (u<=v), per segment
__device__ __forceinline__ int pk0(int a, int b) {
    int u = min(a, b), v = max(a, b);
    return u * 128 - (u * (u - 1)) / 2 + (v - u);
}
__device__ __forceinline__ int pk1(int a, int b) {
    int u = min(a, b), v = max(a, b);
    return BASE1 + u * 64 - (u * (u - 1)) / 2 + (v - u);
}
__device__ __forceinline__ int pk2(int a, int b) {
    int u = min(a, b), v = max(a, b);
    return BASE2 + u * 32 - (u * (u - 1)) / 2 + (v - u);
}

// ---------------------------------------------------------------- uv table (one launch)
// tab[i] = seg<<14 | u<<7 | v  for packed index i (u<=v); pad -> 0xFFFF
__global__ __launch_bounds__(256) void k_uvall(u16* __restrict__ tab) {
    int j = blockIdx.x * 256 + threadIdx.x;
    if (j < 16384) {
        int u = j >> 7, v = j & 127;
        if (v >= u) tab[pk0(u, v)] = (u16)((u << 7) | v);
    } else if (j < 20480) {
        int k = j - 16384, u = k >> 6, v = k & 63;
        if (v >= u) tab[pk1(u, v)] = (u16)((1 << 14) | (u << 7) | v);
    } else if (j < 21504) {
        int k = j - 20480, u = k >> 5, v = k & 31;
        if (v >= u) tab[pk2(u, v)] = (u16)((2 << 14) | (u << 7) | v);
    } else {
        int k = j - 21504;
        if (NVALID + k < NPACK) tab[NVALID + k] = 0xFFFFu;
    }
}

// ---------------------------------------------------------------- packed weights
// Wsym[i,h] = s_seg*(w[uv,h]+w[vu,h])  (diag -> 2w, features carry the 0.5)
// Wt[h,i]   = same values transposed (K-contiguous for GEMM1's B operand)
__global__ __launch_bounds__(256) void k_packw(const float* __restrict__ w0,
                                               const float* __restrict__ w1,
                                               const float* __restrict__ w2,
                                               const u16* __restrict__ tab,
                                               u16* __restrict__ Wsym,
                                               u16* __restrict__ Wt) {
    __shared__ u16 tile[32][258];
    __shared__ u16 te[32];
    int i0 = blockIdx.x * 32, h0 = blockIdx.y * 256, tid = threadIdx.x;
    if (tid < 32) te[tid] = tab[i0 + tid];
    __syncthreads();
    const float s1 = 0.57735026918962576f, s2 = 0.44721359549995794f;
    for (int il = 0; il < 32; il++) {
        unsigned e = te[il];
        float val = 0.f;
        if ((e >> 14) != 3) {
            int seg = e >> 14, u = (e >> 7) & 127, v = e & 127;
            const float* wb; int S; float sc;
            if (seg == 0)      { wb = w0; S = 128; sc = 1.f; }
            else if (seg == 1) { wb = w1; S = 64;  sc = s1; }
            else               { wb = w2; S = 32;  sc = s2; }
            val = sc * (wb[(size_t)(u * S + v) * 1024 + h0 + tid] +
                        wb[(size_t)(v * S + u) * 1024 + h0 + tid]);
        }
        u16 bv = f2bf(val);
        Wsym[(size_t)(i0 + il) * 1024 + h0 + tid] = bv;
        tile[il][tid] = bv;
    }
    __syncthreads();
    union { u16 a[32]; uint4 q[4]; } pk;
#pragma unroll
    for (int il = 0; il < 32; il++) pk.a[il] = tile[il][tid];
    uint4* dst = (uint4*)(Wt + (size_t)(h0 + tid) * NPACK + i0);
#pragma unroll
    for (int q = 0; q < 4; q++) dst[q] = pk.q[q];
}

// ---------------------------------------------------------------- converts
__global__ __launch_bounds__(256) void k_convert(const float* __restrict__ in,
                                                 u16* __restrict__ out, int n4) {
    int i = blockIdx.x * 256 + threadIdx.x;
    if (i >= n4) return;
    float4 v = ((const float4*)in)[i];
    union { u16 a[4]; unsigned long long q; } o;
    o.a[0] = f2bf(v.x); o.a[1] = f2bf(v.y); o.a[2] = f2bf(v.z); o.a[3] = f2bf(v.w);
    ((unsigned long long*)out)[i] = o.q;
}

// out[(c)*ldOut + r] = bf16(in[r*C + c]);  grid = (C/32, R/32)
__global__ __launch_bounds__(256) void k_transpose(const float* __restrict__ in, int R, int C,
                                                   u16* __restrict__ out, int ldOut) {
    __shared__ float tile[32][33];
    int tr0 = blockIdx.y * 32;
    int tc0 = blockIdx.x * 32;
    int lr = threadIdx.x >> 5;
    int lc = threadIdx.x & 31;
#pragma unroll
    for (int i = 0; i < 4; i++) {
        int rr = lr + i * 8;
        tile[rr][lc] = in[(size_t)(tr0 + rr) * C + tc0 + lc];
    }
    __syncthreads();
#pragma unroll
    for (int i = 0; i < 4; i++) {
        int rr = lr + i * 8;
        out[(size_t)(tc0 + rr) * ldOut + tr0 + lc] = f2bf(tile[lc][rr]);
    }
}

// ---------------------------------------------------------------- packed features
__global__ __launch_bounds__(256) void k_features_pack(const float* __restrict__ t,
                                                       const u16* __restrict__ tab,
                                                       u16* __restrict__ P) {
    __shared__ u16 tab_s[NPACK];
    __shared__ float tr[480];
    int b = blockIdx.x, tid = threadIdx.x;
    for (int j = tid; j < NPACK / 8; j += 256)
        ((uint4*)tab_s)[j] = ((const uint4*)tab)[j];
    for (int j = tid; j < 480; j += 256) tr[j] = t[(size_t)b * 480 + j];
    __syncthreads();
    u16* row = P + (size_t)b * NPACK;
    for (int i = tid; i < NPACK; i += 256) {
        unsigned e = tab_s[i];
        float p = 0.f;
        if ((e >> 14) != 3) {
            int seg = e >> 14, u = (e >> 7) & 127, v = e & 127;
            if (seg == 0) p = tr[u] * tr[v];
            else if (seg == 1) {
                const float* x1 = tr + 128;
                p = x1[u*3]*x1[v*3] + x1[u*3+1]*x1[v*3+1] + x1[u*3+2]*x1[v*3+2];
            } else {
                const float* x2 = tr + 320;
#pragma unroll
                for (int m = 0; m < 5; m++) p += x2[u*5+m] * x2[v*5+m];
            }
            if (u == v) p *= 0.5f;
        }
        row[i] = f2bf(p);
    }
}

// ---------------------------------------------------------------- GEMM (NT, BK=64)
// LDS chunk-XOR swizzle: physical 16B chunk = logical ^ ((row>>1)&3). Staging
// lane fetches logical chunk (lane&3)^((lane>>3)&3); reader XORs kq8 with
// (ml>>1)&3. Spreads the b128 fragment reads over all 32 banks (2-way max).
// swz 0: 3-D grid (n,m,sk). swz 1: 1-D 1024 = (sk&7) x 16m x 8n (GEMM1).
// swz 2: 1-D 1408 = 8c x (r%11 -> n-group) x (r/11 -> m).
__global__ __launch_bounds__(256) void k_gemm2(const u16* __restrict__ A, int ldA,
                                               const u16* __restrict__ B, int ldB,
                                               int kLen, float scale,
                                               const float* __restrict__ bias,
                                               float* __restrict__ Cf,
                                               u16* __restrict__ Cb, int ldC,
                                               float* __restrict__ Cpart, int Mtot,
                                               int swz) {
    __shared__ u16 As[2][128 * 32];
    __shared__ u16 Bs[2][128 * 32];
    const int tid = threadIdx.x;
    const int wave = tid >> 6, lane = tid & 63;
    const int wm = wave >> 1, wn = wave & 1;
    int nT, mT, z;
    if (swz == 1) {
        int L = blockIdx.x;
        z = L & 7; int r = L >> 3;
        nT = r >> 4; mT = r & 15;
    } else if (swz == 2) {
        int L = blockIdx.x;
        int c = L & 7, r = L >> 3;
        nT = (r % 11) * 8 + c; mT = r / 11; z = 0;
    } else {
        nT = blockIdx.x; mT = blockIdx.y; z = blockIdx.z;
    }
    const int m0 = mT * 128, n0 = nT * 128;
    const size_t kOff = (size_t)z * kLen;

    const int chl = (((lane & 3) ^ ((lane >> 3) & 3))) * 8;   // logical chunk (swizzled src)
    const u16* aG = A + (size_t)(m0 + wave * 32 + (lane >> 2)) * ldA + kOff + chl;
    const u16* bG = B + (size_t)(n0 + wave * 32 + (lane >> 2)) * ldB + kOff + chl;
    const size_t aS = (size_t)16 * ldA;
    const size_t bS = (size_t)16 * ldB;
    u16* aL0 = &As[0][(wave * 32) * 32];
    u16* aL1 = &As[0][(wave * 32 + 16) * 32];
    u16* aH0 = &As[1][(wave * 32) * 32];
    u16* aH1 = &As[1][(wave * 32 + 16) * 32];
    u16* bL0 = &Bs[0][(wave * 32) * 32];
    u16* bL1 = &Bs[0][(wave * 32 + 16) * 32];
    u16* bH0 = &Bs[1][(wave * 32) * 32];
    u16* bH1 = &Bs[1][(wave * 32 + 16) * 32];

    f32x4 acc[4][4];
#pragma unroll
    for (int i = 0; i < 4; i++)
#pragma unroll
        for (int j = 0; j < 4; j++) acc[i][j] = (f32x4){0.f, 0.f, 0.f, 0.f};

    const int ml = lane & 15, kq8 = lane >> 4;
    const int kqs = (kq8 ^ ((ml >> 1) & 3)) * 8;              // swizzled read offset
    const u16* aRd0 = &As[0][(wm * 64 + ml) * 32 + kqs];
    const u16* bRd0 = &Bs[0][(wn * 64 + ml) * 32 + kqs];
    const u16* aRd1 = &As[1][(wm * 64 + ml) * 32 + kqs];
    const u16* bRd1 = &Bs[1][(wn * 64 + ml) * 32 + kqs];

    for (int k = 0; k < kLen; k += 64) {
        GLOAD_LDS16(aG, aL0);
        GLOAD_LDS16(aG + aS, aL1);
        GLOAD_LDS16(aG + 32, aH0);
        GLOAD_LDS16(aG + aS + 32, aH1);
        GLOAD_LDS16(bG, bL0);
        GLOAD_LDS16(bG + bS, bL1);
        GLOAD_LDS16(bG + 32, bH0);
        GLOAD_LDS16(bG + bS + 32, bH1);
        aG += 64; bG += 64;
        __syncthreads();
        {
            bf16x8 af[4], bfv[4];
#pragma unroll
            for (int i = 0; i < 4; i++) af[i]  = *(const bf16x8*)(aRd0 + i * 16 * 32);
#pragma unroll
            for (int j = 0; j < 4; j++) bfv[j] = *(const bf16x8*)(bRd0 + j * 16 * 32);
#pragma unroll
            for (int i = 0; i < 4; i++)
#pragma unroll
                for (int j = 0; j < 4; j++)
                    acc[i][j] = __builtin_amdgcn_mfma_f32_16x16x32_bf16(af[i], bfv[j], acc[i][j], 0, 0, 0);
        }
        {
            bf16x8 af[4], bfv[4];
#pragma unroll
            for (int i = 0; i < 4; i++) af[i]  = *(const bf16x8*)(aRd1 + i * 16 * 32);
#pragma unroll
            for (int j = 0; j < 4; j++) bfv[j] = *(const bf16x8*)(bRd1 + j * 16 * 32);
#pragma unroll
            for (int i = 0; i < 4; i++)
#pragma unroll
                for (int j = 0; j < 4; j++)
                    acc[i][j] = __builtin_amdgcn_mfma_f32_16x16x32_bf16(af[i], bfv[j], acc[i][j], 0, 0, 0);
        }
        __syncthreads();
    }

    const int q = lane >> 4, nl = lane & 15;   // C/D: col=lane&15, row=(lane>>4)*4+reg
    if (Cpart) {
        float* outP = Cpart + (size_t)z * Mtot * ldC;
#pragma unroll
        for (int i = 0; i < 4; i++)
#pragma unroll
            for (int j = 0; j < 4; j++)
#pragma unroll
                for (int reg = 0; reg < 4; reg++) {
                    int row = m0 + wm * 64 + i * 16 + q * 4 + reg;
                    int col = n0 + wn * 64 + j * 16 + nl;
                    outP[(size_t)row * ldC + col] = acc[i][j][reg];
                }
    } else {
#pragma unroll
        for (int i = 0; i < 4; i++)
#pragma unroll
            for (int j = 0; j < 4; j++)
#pragma unroll
                for (int reg = 0; reg < 4; reg++) {
                    int row = m0 + wm * 64 + i * 16 + q * 4 + reg;
                    int col = n0 + wn * 64 + j * 16 + nl;
                    float v = acc[i][j][reg] * scale + (bias ? bias[col] : 0.0f);
                    if (Cf) Cf[(size_t)row * ldC + col] = v;
                    else    Cb[(size_t)row * ldC + col] = f2bf(v);
                }
    }
}

// sum split-K partials + epilogue
__global__ __launch_bounds__(256) void k_reduce(const float* __restrict__ part, size_t stride,
                                                int SK, int total, int N, float scale,
                                                const float* __restrict__ bias,
                                                float* __restrict__ outF, u16* __restrict__ outB) {
    int i = blockIdx.x * 256 + threadIdx.x;
    if (i >= total) return;
    float s = 0.f;
    for (int z = 0; z < SK; z++) s += part[(size_t)z * stride + i];
    float v = s * scale + (bias ? bias[i % N] : 0.0f);
    if (outF) outF[i] = v;
    else      outB[i] = f2bf(v);
}

// ---------------------------------------------------------------- rowwise LN
__device__ __forceinline__ float blockReduce(float v, float* red) {
#pragma unroll
    for (int off = 32; off > 0; off >>= 1) v += __shfl_down(v, off);
    __syncthreads();
    if ((threadIdx.x & 63) == 0) red[threadIdx.x >> 6] = v;
    __syncthreads();
    return red[0] + red[1] + red[2] + red[3];
}

__global__ __launch_bounds__(256) void k_ln_fwd(const float* __restrict__ X, int D,
    const float* __restrict__ g, const float* __restrict__ be,
    float* __restrict__ mu_out, float* __restrict__ r_out,
    u16* __restrict__ a_bf, float* __restrict__ a_f32) {
    __shared__ float red[4];
    int b = blockIdx.x, tid = threadIdx.x;
    const float* x = X + (size_t)b * D;
    int nd = D >> 8;
    float s = 0.f, s2 = 0.f;
    for (int r = 0; r < nd; r++) { float v = x[tid + (r << 8)]; s += v; s2 += v * v; }
    s = blockReduce(s, red);
    s2 = blockReduce(s2, red);
    float mu = s / D;
    float var = s2 / D - mu * mu;
    float rst = rsqrtf(var + 1e-6f);
    if (tid == 0) { mu_out[b] = mu; r_out[b] = rst; }
    for (int r = 0; r < nd; r++) {
        int i = tid + (r << 8);
        float xh = (x[i] - mu) * rst;
        float ln = xh * g[i] + be[i];
        float a = ln / (1.0f + expf(-ln));
        if (a_bf)  a_bf[(size_t)b * D + i] = f2bf(a);
        if (a_f32) a_f32[(size_t)b * D + i] = a;
    }
}

__global__ __launch_bounds__(256) void k_ln_bwd(const float* __restrict__ dup,
    const float* __restrict__ X, const float* __restrict__ mu_in, const float* __restrict__ r_in,
    const float* __restrict__ g, const float* __restrict__ be,
    u16* __restrict__ out_bf, int D) {
    __shared__ float red[4];
    int b = blockIdx.x, tid = threadIdx.x;
    const float* x = X + (size_t)b * D;
    float mu = mu_in[b], rst = r_in[b];
    int nd = D >> 8;
    float w_[4], xh_[4];
    float sw = 0.f, swx = 0.f;
    for (int r = 0; r < nd; r++) {
        int i = tid + (r << 8);
        float xh = (x[i] - mu) * rst;
        float ln = xh * g[i] + be[i];
        float sg = 1.0f / (1.0f + expf(-ln));
        float dsilu = sg * (1.0f + ln * (1.0f - sg));
        float d = dup ? dup[(size_t)b * D + i] : 1.0f;
        float w = g[i] * dsilu * d;
        w_[r] = w; xh_[r] = xh;
        sw += w; swx += w * xh;
    }
    sw = blockReduce(sw, red);
    swx = blockReduce(swx, red);
    float invD = 1.0f / D;
    for (int r = 0; r < nd; r++) {
        int i = tid + (r << 8);
        float dx = rst * (w_[r] - sw * invD - xh_[r] * swx * invD);
        out_bf[(size_t)b * D + i] = f2bf(dx);
    }
}

// ---------------------------------------------------------------- packed contraction
// y[b,a] = sum_v Gsym[a,v] x[v],  Gsym[a,v] = Gp[pack(a,v)] (scales folded into Wsym).
__global__ __launch_bounds__(256) void k_contract_p(const u16* __restrict__ Gp,
                                                    const float* __restrict__ t,
                                                    float* __restrict__ y) {
    __shared__ u16 gp_s[NPACK];
    __shared__ float xs[480];
    int b = blockIdx.x, tid = threadIdx.x;
    const uint4* gsrc = (const uint4*)(Gp + (size_t)b * NPACK);
    for (int j = tid; j < NPACK / 8; j += 256) ((uint4*)gp_s)[j] = gsrc[j];
    for (int j = tid; j < 480; j += 256) xs[j] = t[(size_t)b * 480 + j];
    __syncthreads();
    int wave = tid >> 6, lane = tid & 63;
    float* yr = y + (size_t)b * 480;
    for (int r = 0; r < 32; r++) {
        int u = wave * 32 + r;
        int v0 = lane, v1 = lane + 64;
        float s = bf2f(gp_s[pk0(u, v0)]) * xs[v0] + bf2f(gp_s[pk0(u, v1)]) * xs[v1];
#pragma unroll
        for (int off = 32; off > 0; off >>= 1) s += __shfl_down(s, off);
        if (lane == 0) yr[u] = s;
    }
    for (int r = 0; r < 16; r++) {
        int u = wave * 16 + r;
        float gv = bf2f(gp_s[pk1(u, lane)]);
        float a0 = gv * xs[128 + lane * 3 + 0];
        float a1 = gv * xs[128 + lane * 3 + 1];
        float a2 = gv * xs[128 + lane * 3 + 2];
#pragma unroll
        for (int off = 32; off > 0; off >>= 1) {
            a0 += __shfl_down(a0, off);
            a1 += __shfl_down(a1, off);
            a2 += __shfl_down(a2, off);
        }
        if (lane == 0) {
            yr[128 + u * 3 + 0] = a0;
            yr[128 + u * 3 + 1] = a1;
            yr[128 + u * 3 + 2] = a2;
        }
    }
    for (int r = 0; r < 8; r++) {
        int u = wave * 8 + r;
        bool act = lane < 32;
        float gv = act ? bf2f(gp_s[pk2(u, act ? lane : 0)]) : 0.f;
        float a[5];
#pragma unroll
        for (int m = 0; m < 5; m++)
            a[m] = act ? gv * xs[320 + lane * 5 + m] : 0.f;
#pragma unroll
        for (int off = 32; off > 0; off >>= 1)
#pragma unroll
            for (int m = 0; m < 5; m++) a[m] += __shfl_down(a[m], off);
        if (lane == 0)
#pragma unroll
            for (int m = 0; m < 5; m++) yr[320 + u * 5 + m] = a[m];
    }
}

// ---------------------------------------------------------------- launch
extern "C" void kernel_launch(void* const* d_in, const int* in_sizes, int n_in,
                              void* d_out, int out_size, void* d_ws, size_t ws_size,
                              hipStream_t stream) {
    const float* t   = (const float*)d_in[0];
    const float* w0  = (const float*)d_in[1];
    const float* w1  = (const float*)d_in[2];
    const float* w2  = (const float*)d_in[3];
    const float* W1  = (const float*)d_in[4];
    const float* b1  = (const float*)d_in[5];
    const float* g1  = (const float*)d_in[6];
    const float* be1 = (const float*)d_in[7];
    const float* W2  = (const float*)d_in[8];
    const float* b2  = (const float*)d_in[9];
    const float* g2  = (const float*)d_in[10];
    const float* be2 = (const float*)d_in[11];

    float* xout = (float*)d_out;                    // 2048*256
    float* yout = xout + (size_t)2048 * 256;        // 2048*480

    char* ws = (char*)d_ws;
    size_t off = 0;
    auto alloc = [&](size_t bytes) -> void* {
        void* p = ws + off;
        off += (bytes + 255) & ~(size_t)255;
        return p;
    };
    u16*   PG    = (u16*)alloc((size_t)2048 * NPACK * 2);   // Ppack, later Gp (aliased)
    u16*   Wsym  = (u16*)alloc((size_t)NPACK * 1024 * 2);   // packed Wsym [i,h]
    u16*   Wt    = (u16*)alloc((size_t)1024 * NPACK * 2);   // packed Wsym^T [h,i]
    u16*   uvtab = (u16*)alloc((size_t)NPACK * 2);
    u16*   W1b   = (u16*)alloc((size_t)1024 * 1024 * 2);
    u16*   W1tb  = (u16*)alloc((size_t)1024 * 1024 * 2);
    u16*   W2b   = (u16*)alloc((size_t)1024 * 256 * 2);
    u16*   W2tb  = (u16*)alloc((size_t)256 * 1024 * 2);
    u16*   h_bf  = (u16*)alloc((size_t)2048 * 1024 * 2);
    float* h1pre = (float*)alloc((size_t)2048 * 1024 * 4);
    float* mu1   = (float*)alloc(2048 * 4);
    float* r1    = (float*)alloc(2048 * 4);
    u16*   a1_bf = (u16*)alloc((size_t)2048 * 1024 * 2);
    float* h2pre = (float*)alloc((size_t)2048 * 256 * 4);
    float* mu2   = (float*)alloc(2048 * 4);
    float* r2    = (float*)alloc(2048 * 4);
    u16*   dh2b  = (u16*)alloc((size_t)2048 * 256 * 2);
    float* d_a1  = (float*)alloc((size_t)2048 * 1024 * 4);
    u16*   dh1b  = (u16*)alloc((size_t)2048 * 1024 * 2);
    u16*   de_bf = (u16*)alloc((size_t)2048 * 1024 * 2);
    float* Cpart = (float*)(ws + off);
    size_t cpartBytes = (ws_size > off) ? (ws_size - off) : 0;
    (void)in_sizes; (void)n_in; (void)out_size;

    const float sF = 1.0f / sqrtf(21504.0f);

    // generic GEMM helper (MLP GEMMs): 3-D grid, optional split-K
    auto gemm = [&](const u16* A, int ldA, const u16* B, int ldB, int M, int N, int K,
                    int SKwant, float scale, const float* bias,
                    float* Cf, u16* Cb, int ldC) {
        int SK = SKwant;
        size_t slice = (size_t)M * ldC * 4;
        if (SK > 1 && cpartBytes < 2 * slice) SK = 1;
        if (SK > 1 && (size_t)SK * slice > cpartBytes) SK = (int)(cpartBytes / slice);
        while (SK > 1 && !((K % SK) == 0 && ((K / SK) % 64) == 0)) SK--;
        dim3 grid(N / 128, M / 128, SK);
        if (SK > 1) {
            k_gemm2<<<grid, 256, 0, stream>>>(A, ldA, B, ldB, K / SK, 0.f, nullptr,
                                              nullptr, nullptr, ldC, Cpart, M, 0);
            int total = M * ldC;
            k_reduce<<<(total + 255) / 256, 256, 0, stream>>>(Cpart, (size_t)M * ldC, SK,
                                                              total, N, scale, bias, Cf, Cb);
        } else {
            k_gemm2<<<grid, 256, 0, stream>>>(A, ldA, B, ldB, K, scale, bias,
                                              Cf, Cb, ldC, nullptr, M, 0);
        }
    };

    // index table + packed weights
    k_uvall<<<(21504 + NPACK - NVALID + 255) / 256, 256, 0, stream>>>(uvtab);
    k_packw<<<dim3(NPACK / 32, 4), 256, 0, stream>>>(w0, w1, w2, uvtab, Wsym, Wt);

    // small MLP weights
    k_transpose<<<dim3(32, 32), 256, 0, stream>>>(W1, 1024, 1024, W1tb, 1024);
    k_transpose<<<dim3(8, 32), 256, 0, stream>>>(W2, 1024, 256, W2tb, 1024);
    k_convert<<<1024 * 1024 / 1024, 256, 0, stream>>>(W1, W1b, 1024 * 1024 / 4);
    k_convert<<<1024 * 256 / 1024, 256, 0, stream>>>(W2, W2b, 1024 * 256 / 4);

    // packed features
    k_features_pack<<<2048, 256, 0, stream>>>(t, uvtab, PG);

    // h = sF * Ppack @ Wt^T : K=11264, SK=8 (kLen=1408), XCD-swizzled 1024 blocks
    k_gemm2<<<dim3(1024), 256, 0, stream>>>(PG, NPACK, Wt, NPACK, NPACK / 8, 0.f, nullptr,
                                            nullptr, nullptr, 1024, Cpart, 2048, 1);
    {
        int total = 2048 * 1024;
        k_reduce<<<(total + 255) / 256, 256, 0, stream>>>(Cpart, (size_t)2048 * 1024, 8,
                                                          total, 1024, sF, nullptr,
                                                          nullptr, h_bf);
    }

    // MLP forward
    gemm(h_bf, 1024, W1tb, 1024, 2048, 1024, 1024, 4, 1.0f, b1, h1pre, nullptr, 1024);
    k_ln_fwd<<<2048, 256, 0, stream>>>(h1pre, 1024, g1, be1, mu1, r1, a1_bf, nullptr);
    gemm(a1_bf, 1024, W2tb, 1024, 2048, 256, 1024, 8, 1.0f, b2, h2pre, nullptr, 256);
    k_ln_fwd<<<2048, 256, 0, stream>>>(h2pre, 256, g2, be2, mu2, r2, nullptr, xout);

    // backward
    k_ln_bwd<<<2048, 256, 0, stream>>>(nullptr, h2pre, mu2, r2, g2, be2, dh2b, 256);
    gemm(dh2b, 256, W2b, 256, 2048, 1024, 256, 4, 1.0f, nullptr, d_a1, nullptr, 1024);
    k_ln_bwd<<<2048, 256, 0, stream>>>(d_a1, h1pre, mu1, r1, g1, be1, dh1b, 1024);
    gemm(dh1b, 1024, W1b, 1024, 2048, 1024, 1024, 4, sF, nullptr, nullptr, de_bf, 1024);

    // Gp = de @ Wsym^T (packed N=11264): 1408 blocks, grouped swizzle, bf16 out
    u16* Gp = PG;   // Ppack dead after GEMM1
    k_gemm2<<<dim3(1408), 256, 0, stream>>>(de_bf, 1024, Wsym, 1024, 1024, 1.0f, nullptr,
                                            nullptr, Gp, NPACK, nullptr, 2048, 2);

    // y from packed symmetric Gp (shuffle-reduce, no atomics)
    k_contract_p<<<2048, 256, 0, stream>>>(Gp, t, yout);
}